// Round 2
// baseline (68143.030 us; speedup 1.0000x reference)
//
#include <hip/hip_runtime.h>

#define NB 256
#define NT 512

namespace {
constexpr int kB = 128;
constexpr int kS = 1024;
constexpr int kT = 257;
constexpr int kV = 256;
constexpr int kE = 128;
constexpr int kH = 512;
constexpr int kHB = kH * kB;  // 65536 floats per h buffer
constexpr size_t WS_P    = 4096;
constexpr size_t WS_HT   = 16384;
constexpr size_t WS_ELUT = WS_HT + sizeof(float) * (size_t)(4 * kHB);        // +1 MiB
constexpr size_t WS_DLUT = WS_ELUT + sizeof(float) * (size_t)(NB * kV * 8);  // +2 MiB
constexpr size_t WS_ZERO = WS_HT + sizeof(float) * (size_t)(4 * kHB);
}

struct Ctl { unsigned cnt; unsigned rel; };

__device__ __forceinline__ float sigm(float x) { return 1.0f / (1.0f + expf(-x)); }

__device__ __forceinline__ void gbar(Ctl* ctl, unsigned gen) {
  __syncthreads();
  if (threadIdx.x == 0) {
    unsigned prev = __hip_atomic_fetch_add(&ctl->cnt, 1u, __ATOMIC_ACQ_REL,
                                           __HIP_MEMORY_SCOPE_AGENT);
    if (prev == gen * (unsigned)NB - 1u) {
      __hip_atomic_store(&ctl->rel, gen, __ATOMIC_RELEASE, __HIP_MEMORY_SCOPE_AGENT);
    } else {
      unsigned cur;
      do {
        __builtin_amdgcn_s_sleep(1);
        cur = __hip_atomic_load(&ctl->rel, __ATOMIC_ACQUIRE, __HIP_MEMORY_SCOPE_AGENT);
      } while ((int)(cur - gen) < 0);
    }
  }
  __syncthreads();
}

__device__ __forceinline__ void fma4(float& acc, float h0, float h1, float h2,
                                     float h3, const float4& wv) {
  acc = fmaf(h0, wv.x, acc);
  acc = fmaf(h1, wv.y, acc);
  acc = fmaf(h2, wv.z, acc);
  acc = fmaf(h3, wv.w, acc);
}

__global__ __launch_bounds__(NT, 2) void seq2seq_persistent(
    const int* __restrict__ src, const int* __restrict__ trg,
    const float* __restrict__ enc_emb,
    const float* __restrict__ ew_ih0, const float* __restrict__ ew_hh0,
    const float* __restrict__ eb_ih0, const float* __restrict__ eb_hh0,
    const float* __restrict__ ew_ih1, const float* __restrict__ ew_hh1,
    const float* __restrict__ eb_ih1, const float* __restrict__ eb_hh1,
    const float* __restrict__ dec_emb,
    const float* __restrict__ dw_ih0, const float* __restrict__ dw_hh0,
    const float* __restrict__ db_ih0, const float* __restrict__ db_hh0,
    const float* __restrict__ dw_ih1, const float* __restrict__ dw_hh1,
    const float* __restrict__ db_ih1, const float* __restrict__ db_hh1,
    const float* __restrict__ fc_w, const float* __restrict__ fc_b,
    float* __restrict__ out, char* __restrict__ ws)
{
  // Block n owns hidden units u0=2n, u1=2n+1: 8 gate columns
  // G(c) = (c>=4 ? 2n+1 : 2n) + (c&3)*kH   (c&3: i,f,g,o row-blocks)
  __shared__ float wA[8][kH];   // enc: w_hh0 slice | dec: w_hh0 slice
  __shared__ float wB[8][kH];   // enc: w_ih1       | dec: w_ih1
  __shared__ float wC[8][kH];   // enc: w_hh1       | dec: w_hh1
  __shared__ float fc_sh[kH];
  __shared__ float bC_sh[8];
  __shared__ float g2[16][kB];      // gate scratch (L0: 0..7, L1: 8..15)
  __shared__ float c_sh[2][2][kB];  // persistent cell state [layer][unit][row]

  const int tid = threadIdx.x;
  const int n   = blockIdx.x;
  const int r   = tid & (kB - 1);
  const int cg  = (tid >> 7) & 1;   // column group: cols cbase..cbase+3
  const int kh  = tid >> 8;         // K-half: 0 or 1
  const int cbase = 4 * cg;
  const int kbase = kh * (kH / 2);

  Ctl* ctl = (Ctl*)ws;
  unsigned long long* P = (unsigned long long*)(ws + WS_P);  // packed argmax [2][kB]
  float* hT0 = (float*)(ws + WS_HT);        // [2][kH][kB] transposed h, layer0
  float* hT1 = hT0 + 2 * kHB;               // layer1
  float* elut = (float*)(ws + WS_ELUT);     // [NB][kV][8]
  float* dlut = (float*)(ws + WS_DLUT);

  // ---------------- one-time init ----------------
  for (int i = tid; i < 2 * 2 * kB; i += NT) (&c_sh[0][0][0])[i] = 0.0f;
  for (int i = tid; i < 8 * kH; i += NT) {
    int c = i >> 9, k = i & (kH - 1);
    int gc = ((c & 4) ? 2 * n + 1 : 2 * n) + (c & 3) * kH;
    wA[c][k] = ew_hh0[gc * kH + k];
    wB[c][k] = ew_ih1[gc * kH + k];
    wC[c][k] = ew_hh1[gc * kH + k];
  }
  if (tid < 8) {
    int gc = ((tid & 4) ? 2 * n + 1 : 2 * n) + (tid & 3) * kH;
    bC_sh[tid] = eb_ih1[gc] + eb_hh1[gc];
  }
  {
    // token LUTs: lut[v][c] = emb[v,:] @ w_ih0[G(c),:] + b_ih0 + b_hh0
    int v = tid & (kV - 1);
    int hlf = tid >> 8;
    for (int j = 0; j < 4; ++j) {
      int c = hlf * 4 + j;
      int gc = ((c & 4) ? 2 * n + 1 : 2 * n) + (c & 3) * kH;
      float ae = eb_ih0[gc] + eb_hh0[gc];
      float ad = db_ih0[gc] + db_hh0[gc];
      for (int e = 0; e < kE; ++e) {
        ae = fmaf(enc_emb[v * kE + e], ew_ih0[gc * kE + e], ae);
        ad = fmaf(dec_emb[v * kE + e], dw_ih0[gc * kE + e], ad);
      }
      elut[((size_t)n * kV + v) * 8 + c] = ae;
      dlut[((size_t)n * kV + v) * 8 + c] = ad;
    }
  }
  __syncthreads();

  unsigned gen = 0;

  // ---------------- encoder: layers 0/1 pipelined, 1 barrier per step ----------------
  // phase p: L0 computes t=p (p<kS), L1 computes t'=p-1 (p>=1).
  // hT0: read (p+1)&1, write p&1 ; hT1: read p&1, write (p+1)&1
#pragma unroll 1
  for (int p = 0; p <= kS; ++p) {
    float a0 = 0.f, a1 = 0.f, a2 = 0.f, a3 = 0.f;
    float b0, b1, b2, b3;
    if (kh == 0) {
      int tok = (p < kS) ? src[r * kS + p] : 0;
      const float* lp = elut + ((size_t)n * kV + tok) * 8 + cbase;
      a0 = lp[0]; a1 = lp[1]; a2 = lp[2]; a3 = lp[3];
      b0 = bC_sh[cbase + 0]; b1 = bC_sh[cbase + 1];
      b2 = bC_sh[cbase + 2]; b3 = bC_sh[cbase + 3];
    } else {
      b0 = b1 = b2 = b3 = 0.f;
    }
    const float* h0p = hT0 + ((p + 1) & 1) * kHB + kbase * kB + r;
    const float* h1p = hT1 + (p & 1) * kHB + kbase * kB + r;
    const float* wAb = &wA[cbase][0] + kbase;
    const float* wBb = &wB[cbase][0] + kbase;
    const float* wCb = &wC[cbase][0] + kbase;
#pragma unroll 1
    for (int k4 = 0; k4 < kH / 8; ++k4) {
      int k = k4 * 4;
      float h00 = h0p[(k + 0) * kB], h01 = h0p[(k + 1) * kB];
      float h02 = h0p[(k + 2) * kB], h03 = h0p[(k + 3) * kB];
      float h10 = h1p[(k + 0) * kB], h11 = h1p[(k + 1) * kB];
      float h12 = h1p[(k + 2) * kB], h13 = h1p[(k + 3) * kB];
      float4 wa0 = *(const float4*)(wAb + 0 * kH + k);
      float4 wa1 = *(const float4*)(wAb + 1 * kH + k);
      float4 wa2 = *(const float4*)(wAb + 2 * kH + k);
      float4 wa3 = *(const float4*)(wAb + 3 * kH + k);
      fma4(a0, h00, h01, h02, h03, wa0);
      fma4(a1, h00, h01, h02, h03, wa1);
      fma4(a2, h00, h01, h02, h03, wa2);
      fma4(a3, h00, h01, h02, h03, wa3);
      float4 wb0 = *(const float4*)(wBb + 0 * kH + k);
      float4 wb1 = *(const float4*)(wBb + 1 * kH + k);
      float4 wb2 = *(const float4*)(wBb + 2 * kH + k);
      float4 wb3 = *(const float4*)(wBb + 3 * kH + k);
      fma4(b0, h00, h01, h02, h03, wb0);
      fma4(b1, h00, h01, h02, h03, wb1);
      fma4(b2, h00, h01, h02, h03, wb2);
      fma4(b3, h00, h01, h02, h03, wb3);
      float4 wc0 = *(const float4*)(wCb + 0 * kH + k);
      float4 wc1 = *(const float4*)(wCb + 1 * kH + k);
      float4 wc2 = *(const float4*)(wCb + 2 * kH + k);
      float4 wc3 = *(const float4*)(wCb + 3 * kH + k);
      fma4(b0, h10, h11, h12, h13, wc0);
      fma4(b1, h10, h11, h12, h13, wc1);
      fma4(b2, h10, h11, h12, h13, wc2);
      fma4(b3, h10, h11, h12, h13, wc3);
    }
    // reduce K-halves in LDS
    if (kh == 1) {
      g2[cbase + 0][r] = a0; g2[cbase + 1][r] = a1;
      g2[cbase + 2][r] = a2; g2[cbase + 3][r] = a3;
      g2[8 + cbase + 0][r] = b0; g2[8 + cbase + 1][r] = b1;
      g2[8 + cbase + 2][r] = b2; g2[8 + cbase + 3][r] = b3;
    }
    __syncthreads();
    if (kh == 0) {
      g2[cbase + 0][r] += a0; g2[cbase + 1][r] += a1;
      g2[cbase + 2][r] += a2; g2[cbase + 3][r] += a3;
      g2[8 + cbase + 0][r] += b0; g2[8 + cbase + 1][r] += b1;
      g2[8 + cbase + 2][r] += b2; g2[8 + cbase + 3][r] += b3;
    }
    __syncthreads();
    {
      const int lay = tid >> 8;
      const int ul  = (tid >> 7) & 1;
      const int rr  = tid & (kB - 1);
      const bool act = (lay == 0) ? (p < kS) : (p >= 1);
      if (act) {
        const int base = 8 * lay + 4 * ul;
        float gi = sigm(g2[base + 0][rr]);
        float gf = sigm(g2[base + 1][rr]);
        float gg = tanhf(g2[base + 2][rr]);
        float go = sigm(g2[base + 3][rr]);
        float cc = fmaf(gf, c_sh[lay][ul][rr], gi * gg);
        c_sh[lay][ul][rr] = cc;
        float hv = go * tanhf(cc);
        float* hb = (lay == 0) ? (hT0 + (p & 1) * kHB) : (hT1 + ((p + 1) & 1) * kHB);
        hb[(2 * n + ul) * kB + rr] = hv;
      }
    }
    gbar(ctl, ++gen);
  }

  // ---------------- restage LDS for decoder ----------------
  for (int i = tid; i < 8 * kH; i += NT) {
    int c = i >> 9, k = i & (kH - 1);
    int gc = ((c & 4) ? 2 * n + 1 : 2 * n) + (c & 3) * kH;
    wA[c][k] = dw_hh0[gc * kH + k];
    wB[c][k] = dw_ih1[gc * kH + k];
    wC[c][k] = dw_hh1[gc * kH + k];
  }
  for (int i = tid; i < kH; i += NT) fc_sh[i] = fc_w[n * kH + i];
  if (tid < 8) {
    int gc = ((tid & 4) ? 2 * n + 1 : 2 * n) + (tid & 3) * kH;
    bC_sh[tid] = db_ih1[gc] + db_hh1[gc];
  }
  const float fcb = fc_b[n];
  __syncthreads();

  // ---------------- decoder: 256 greedy steps, 3 barriers each ----------------
  // step t: h0 read buf t&1, write (t&1)^1 ; h1 read t&1, write (t&1)^1
#pragma unroll 1
  for (int t = 1; t <= kT - 1; ++t) {
    // ---- D1: cell0 ----
    int tok;
    if (t == 1) {
      tok = trg[r * kT];
    } else {
      unsigned long long pk = P[((t - 1) & 1) * kB + r];
      tok = 255 - (int)(unsigned)(pk & 0xffffffffull);
    }
    {
      float a0 = 0.f, a1 = 0.f, a2 = 0.f, a3 = 0.f;
      if (kh == 0) {
        const float* lp = dlut + ((size_t)n * kV + tok) * 8 + cbase;
        a0 = lp[0]; a1 = lp[1]; a2 = lp[2]; a3 = lp[3];
      }
      const float* h0p = hT0 + (t & 1) * kHB + kbase * kB + r;
      const float* wAb = &wA[cbase][0] + kbase;
#pragma unroll 2
      for (int k4 = 0; k4 < kH / 8; ++k4) {
        int k = k4 * 4;
        float h00 = h0p[(k + 0) * kB], h01 = h0p[(k + 1) * kB];
        float h02 = h0p[(k + 2) * kB], h03 = h0p[(k + 3) * kB];
        float4 wa0 = *(const float4*)(wAb + 0 * kH + k);
        float4 wa1 = *(const float4*)(wAb + 1 * kH + k);
        float4 wa2 = *(const float4*)(wAb + 2 * kH + k);
        float4 wa3 = *(const float4*)(wAb + 3 * kH + k);
        fma4(a0, h00, h01, h02, h03, wa0);
        fma4(a1, h00, h01, h02, h03, wa1);
        fma4(a2, h00, h01, h02, h03, wa2);
        fma4(a3, h00, h01, h02, h03, wa3);
      }
      if (kh == 1) {
        g2[cbase + 0][r] = a0; g2[cbase + 1][r] = a1;
        g2[cbase + 2][r] = a2; g2[cbase + 3][r] = a3;
      }
      __syncthreads();
      if (kh == 0) {
        g2[cbase + 0][r] += a0; g2[cbase + 1][r] += a1;
        g2[cbase + 2][r] += a2; g2[cbase + 3][r] += a3;
      }
      __syncthreads();
      if (tid < 256) {
        const int ul = tid >> 7, rr = tid & (kB - 1);
        const int base = 4 * ul;
        float gi = sigm(g2[base + 0][rr]);
        float gf = sigm(g2[base + 1][rr]);
        float gg = tanhf(g2[base + 2][rr]);
        float go = sigm(g2[base + 3][rr]);
        float cc = fmaf(gf, c_sh[0][ul][rr], gi * gg);
        c_sh[0][ul][rr] = cc;
        (hT0 + ((t & 1) ^ 1) * kHB)[(2 * n + ul) * kB + rr] = go * tanhf(cc);
      }
    }
    gbar(ctl, ++gen);

    // ---- D2: cell1 (+ reset next argmax buffer) ----
    {
      float b0, b1, b2, b3;
      if (kh == 0) {
        b0 = bC_sh[cbase + 0]; b1 = bC_sh[cbase + 1];
        b2 = bC_sh[cbase + 2]; b3 = bC_sh[cbase + 3];
      } else {
        b0 = b1 = b2 = b3 = 0.f;
      }
      const float* h0n = hT0 + ((t & 1) ^ 1) * kHB + kbase * kB + r;
      const float* h1p = hT1 + (t & 1) * kHB + kbase * kB + r;
      const float* wBb = &wB[cbase][0] + kbase;
      const float* wCb = &wC[cbase][0] + kbase;
#pragma unroll 1
      for (int k4 = 0; k4 < kH / 8; ++k4) {
        int k = k4 * 4;
        float h00 = h0n[(k + 0) * kB], h01 = h0n[(k + 1) * kB];
        float h02 = h0n[(k + 2) * kB], h03 = h0n[(k + 3) * kB];
        float h10 = h1p[(k + 0) * kB], h11 = h1p[(k + 1) * kB];
        float h12 = h1p[(k + 2) * kB], h13 = h1p[(k + 3) * kB];
        float4 wb0 = *(const float4*)(wBb + 0 * kH + k);
        float4 wb1 = *(const float4*)(wBb + 1 * kH + k);
        float4 wb2 = *(const float4*)(wBb + 2 * kH + k);
        float4 wb3 = *(const float4*)(wBb + 3 * kH + k);
        fma4(b0, h00, h01, h02, h03, wb0);
        fma4(b1, h00, h01, h02, h03, wb1);
        fma4(b2, h00, h01, h02, h03, wb2);
        fma4(b3, h00, h01, h02, h03, wb3);
        float4 wc0 = *(const float4*)(wCb + 0 * kH + k);
        float4 wc1 = *(const float4*)(wCb + 1 * kH + k);
        float4 wc2 = *(const float4*)(wCb + 2 * kH + k);
        float4 wc3 = *(const float4*)(wCb + 3 * kH + k);
        fma4(b0, h10, h11, h12, h13, wc0);
        fma4(b1, h10, h11, h12, h13, wc1);
        fma4(b2, h10, h11, h12, h13, wc2);
        fma4(b3, h10, h11, h12, h13, wc3);
      }
      if (kh == 1) {
        g2[cbase + 0][r] = b0; g2[cbase + 1][r] = b1;
        g2[cbase + 2][r] = b2; g2[cbase + 3][r] = b3;
      }
      __syncthreads();
      if (kh == 0) {
        g2[cbase + 0][r] += b0; g2[cbase + 1][r] += b1;
        g2[cbase + 2][r] += b2; g2[cbase + 3][r] += b3;
      }
      if (tid < kB) P[(t & 1) * kB + tid] = 0ull;  // reset this step's argmax buf
      __syncthreads();
      if (tid < 256) {
        const int ul = tid >> 7, rr = tid & (kB - 1);
        const int base = 4 * ul;
        float gi = sigm(g2[base + 0][rr]);
        float gf = sigm(g2[base + 1][rr]);
        float gg = tanhf(g2[base + 2][rr]);
        float go = sigm(g2[base + 3][rr]);
        float cc = fmaf(gf, c_sh[1][ul][rr], gi * gg);
        c_sh[1][ul][rr] = cc;
        (hT1 + ((t & 1) ^ 1) * kHB)[(2 * n + ul) * kB + rr] = go * tanhf(cc);
      }
    }
    gbar(ctl, ++gen);

    // ---- D3: fc (col n) + packed atomic argmax ----
    {
      const float* h1n = hT1 + ((t & 1) ^ 1) * kHB;
      const int kq = tid >> 7;  // K-quarter
      float part = 0.f;
      const float* hp = h1n + (kq * 128) * kB + r;
      const float* fp = fc_sh + kq * 128;
#pragma unroll 4
      for (int k4 = 0; k4 < 32; ++k4) {
        int k = k4 * 4;
        float4 w = *(const float4*)(fp + k);
        part = fmaf(hp[(k + 0) * kB], w.x, part);
        part = fmaf(hp[(k + 1) * kB], w.y, part);
        part = fmaf(hp[(k + 2) * kB], w.z, part);
        part = fmaf(hp[(k + 3) * kB], w.w, part);
      }
      ((float*)g2)[kq * kB + r] = part;
      __syncthreads();
      if (tid < kB) {
        float* gf = (float*)g2;
        float logit = gf[tid] + gf[kB + tid] + gf[2 * kB + tid] + gf[3 * kB + tid] + fcb;
        out[((size_t)tid * 256 + (t - 1)) * 256 + n] = logit;
        unsigned bits = __float_as_uint(logit);
        unsigned key = (bits & 0x80000000u) ? ~bits : (bits | 0x80000000u);
        unsigned long long pk =
            ((unsigned long long)key << 32) | (unsigned long long)(255 - n);
        atomicMax(&P[(t & 1) * kB + tid], pk);
      }
    }
    gbar(ctl, ++gen);
  }
}

extern "C" void kernel_launch(void* const* d_in, const int* in_sizes, int n_in,
                              void* d_out, int out_size, void* d_ws, size_t ws_size,
                              hipStream_t stream) {
  (void)in_sizes; (void)n_in; (void)out_size; (void)ws_size;
  hipMemsetAsync(d_ws, 0, WS_ZERO, stream);  // barrier ctl + argmax bufs + h buffers
  hipLaunchKernelGGL(seq2seq_persistent, dim3(NB), dim3(NT), 0, stream,
    (const int*)d_in[0], (const int*)d_in[1],
    (const float*)d_in[2],
    (const float*)d_in[3], (const float*)d_in[4],
    (const float*)d_in[5], (const float*)d_in[6],
    (const float*)d_in[7], (const float*)d_in[8],
    (const float*)d_in[9], (const float*)d_in[10],
    (const float*)d_in[11],
    (const float*)d_in[12], (const float*)d_in[13],
    (const float*)d_in[14], (const float*)d_in[15],
    (const float*)d_in[16], (const float*)d_in[17],
    (const float*)d_in[18], (const float*)d_in[19],
    (const float*)d_in[20], (const float*)d_in[21],
    (float*)d_out, (char*)d_ws);
}

// Round 3
// 60577.423 us; speedup vs baseline: 1.1249x; 1.1249x over previous
//
#include <hip/hip_runtime.h>

#define NB 256
#define NT 512

namespace {
constexpr int kB = 128;
constexpr int kS = 1024;
constexpr int kT = 257;
constexpr int kV = 256;
constexpr int kE = 128;
constexpr int kH = 512;
constexpr int kHB = kH * kB;  // 65536 floats per h buffer
// ws layout
constexpr size_t WS_REL  = 0;                                   // u32 release word
constexpr size_t WS_ARR  = 1024;                                // 256 flags, 64B apart
constexpr size_t WS_P    = 18432;                               // packed argmax [2][kB]
constexpr size_t WS_HT   = 20480;                               // [4][kH][kB] h buffers
constexpr size_t WS_ELUT = WS_HT + sizeof(float) * (size_t)(4 * kHB);
constexpr size_t WS_DLUT = WS_ELUT + sizeof(float) * (size_t)(NB * kV * 8);
constexpr size_t WS_ZERO = WS_HT + sizeof(float) * (size_t)(4 * kHB);
}

__device__ __forceinline__ float sigm(float x) { return 1.0f / (1.0f + expf(-x)); }

// Contention-free grid barrier: per-block arrival flags (64B apart, plain
// release stores), block 0 aggregates, single release word broadcast.
__device__ __forceinline__ void gbar(char* ws, int n, unsigned gen) {
  __syncthreads();
  const int tid = threadIdx.x;
  unsigned* rel = (unsigned*)(ws + WS_REL);
  unsigned* arr = (unsigned*)(ws + WS_ARR);
  if (n == 0) {
    if (tid >= 1 && tid < NB) {
      while (__hip_atomic_load(&arr[tid * 16], __ATOMIC_RELAXED,
                               __HIP_MEMORY_SCOPE_AGENT) < gen)
        __builtin_amdgcn_s_sleep(1);
      __builtin_amdgcn_fence(__ATOMIC_ACQUIRE, "agent");
    }
    __syncthreads();
    if (tid == 0)
      __hip_atomic_store(rel, gen, __ATOMIC_RELEASE, __HIP_MEMORY_SCOPE_AGENT);
  } else {
    if (tid == 0) {
      __hip_atomic_store(&arr[n * 16], gen, __ATOMIC_RELEASE,
                         __HIP_MEMORY_SCOPE_AGENT);
      while (__hip_atomic_load(rel, __ATOMIC_RELAXED,
                               __HIP_MEMORY_SCOPE_AGENT) < gen)
        __builtin_amdgcn_s_sleep(1);
      __builtin_amdgcn_fence(__ATOMIC_ACQUIRE, "agent");
    }
  }
  __syncthreads();
}

__device__ __forceinline__ void fma4(float& acc, float h0, float h1, float h2,
                                     float h3, const float4& wv) {
  acc = fmaf(h0, wv.x, acc);
  acc = fmaf(h1, wv.y, acc);
  acc = fmaf(h2, wv.z, acc);
  acc = fmaf(h3, wv.w, acc);
}

__global__ __launch_bounds__(NT, 2) void seq2seq_persistent(
    const int* __restrict__ src, const int* __restrict__ trg,
    const float* __restrict__ enc_emb,
    const float* __restrict__ ew_ih0, const float* __restrict__ ew_hh0,
    const float* __restrict__ eb_ih0, const float* __restrict__ eb_hh0,
    const float* __restrict__ ew_ih1, const float* __restrict__ ew_hh1,
    const float* __restrict__ eb_ih1, const float* __restrict__ eb_hh1,
    const float* __restrict__ dec_emb,
    const float* __restrict__ dw_ih0, const float* __restrict__ dw_hh0,
    const float* __restrict__ db_ih0, const float* __restrict__ db_hh0,
    const float* __restrict__ dw_ih1, const float* __restrict__ dw_hh1,
    const float* __restrict__ db_ih1, const float* __restrict__ db_hh1,
    const float* __restrict__ fc_w, const float* __restrict__ fc_b,
    float* __restrict__ out, char* __restrict__ ws)
{
  // Block n owns hidden units u0=2n, u1=2n+1: 8 gate columns
  // G(c) = (c>=4 ? 2n+1 : 2n) + (c&3)*kH   (c&3: i,f,g,o row-blocks)
  __shared__ float wA[8][kH];   // enc: w_hh0 slice | dec: w_hh0 slice
  __shared__ float wB[8][kH];   // enc: w_ih1       | dec: w_ih1
  __shared__ float wC[8][kH];   // enc: w_hh1       | dec: w_hh1
  __shared__ float fc_sh[kH];
  __shared__ float bC_sh[8];
  __shared__ float g2[16][kB];      // gate scratch (L0: 0..7, L1: 8..15)
  __shared__ float c_sh[2][2][kB];  // persistent cell state [layer][unit][row]

  const int tid = threadIdx.x;
  const int n   = blockIdx.x;
  const int r   = tid & (kB - 1);
  const int cg  = (tid >> 7) & 1;   // column group: cols cbase..cbase+3
  const int kh  = tid >> 8;         // K-half: 0 or 1
  const int cbase = 4 * cg;
  const int kbase = kh * (kH / 2);

  unsigned long long* P = (unsigned long long*)(ws + WS_P);  // packed argmax [2][kB]
  float* hT0 = (float*)(ws + WS_HT);        // [2][kH][kB] transposed h, layer0
  float* hT1 = hT0 + 2 * kHB;               // layer1
  float* elut = (float*)(ws + WS_ELUT);     // [NB][kV][8]
  float* dlut = (float*)(ws + WS_DLUT);

  // ---------------- one-time init ----------------
  for (int i = tid; i < 2 * 2 * kB; i += NT) (&c_sh[0][0][0])[i] = 0.0f;
  for (int i = tid; i < 8 * kH; i += NT) {
    int c = i >> 9, k = i & (kH - 1);
    int gc = ((c & 4) ? 2 * n + 1 : 2 * n) + (c & 3) * kH;
    wA[c][k] = ew_hh0[gc * kH + k];
    wB[c][k] = ew_ih1[gc * kH + k];
    wC[c][k] = ew_hh1[gc * kH + k];
  }
  if (tid < 8) {
    int gc = ((tid & 4) ? 2 * n + 1 : 2 * n) + (tid & 3) * kH;
    bC_sh[tid] = eb_ih1[gc] + eb_hh1[gc];
  }
  {
    // token LUTs: lut[v][c] = emb[v,:] @ w_ih0[G(c),:] + b_ih0 + b_hh0
    int v = tid & (kV - 1);
    int hlf = tid >> 8;
    for (int j = 0; j < 4; ++j) {
      int c = hlf * 4 + j;
      int gc = ((c & 4) ? 2 * n + 1 : 2 * n) + (c & 3) * kH;
      float ae = eb_ih0[gc] + eb_hh0[gc];
      float ad = db_ih0[gc] + db_hh0[gc];
      for (int e = 0; e < kE; ++e) {
        ae = fmaf(enc_emb[v * kE + e], ew_ih0[gc * kE + e], ae);
        ad = fmaf(dec_emb[v * kE + e], dw_ih0[gc * kE + e], ad);
      }
      elut[((size_t)n * kV + v) * 8 + c] = ae;
      dlut[((size_t)n * kV + v) * 8 + c] = ad;
    }
  }
  __syncthreads();

  unsigned gen = 0;

  // ---------------- encoder: layers 0/1 pipelined, 1 barrier per step ----------------
  // phase p: L0 computes t=p (p<kS), L1 computes t'=p-1 (p>=1).
  // hT0: read (p+1)&1, write p&1 ; hT1: read p&1, write (p+1)&1
#pragma unroll 1
  for (int p = 0; p <= kS; ++p) {
    float a0 = 0.f, a1 = 0.f, a2 = 0.f, a3 = 0.f;
    float b0, b1, b2, b3;
    if (kh == 0) {
      int tok = (p < kS) ? src[r * kS + p] : 0;
      const float* lp = elut + ((size_t)n * kV + tok) * 8 + cbase;
      a0 = lp[0]; a1 = lp[1]; a2 = lp[2]; a3 = lp[3];
      b0 = bC_sh[cbase + 0]; b1 = bC_sh[cbase + 1];
      b2 = bC_sh[cbase + 2]; b3 = bC_sh[cbase + 3];
    } else {
      b0 = b1 = b2 = b3 = 0.f;
    }
    const float* h0p = hT0 + ((p + 1) & 1) * kHB + kbase * kB + r;
    const float* h1p = hT1 + (p & 1) * kHB + kbase * kB + r;
    const float* wAb = &wA[cbase][0] + kbase;
    const float* wBb = &wB[cbase][0] + kbase;
    const float* wCb = &wC[cbase][0] + kbase;
#pragma unroll 2
    for (int k4 = 0; k4 < kH / 8; ++k4) {
      int k = k4 * 4;
      float h00 = h0p[(k + 0) * kB], h01 = h0p[(k + 1) * kB];
      float h02 = h0p[(k + 2) * kB], h03 = h0p[(k + 3) * kB];
      float h10 = h1p[(k + 0) * kB], h11 = h1p[(k + 1) * kB];
      float h12 = h1p[(k + 2) * kB], h13 = h1p[(k + 3) * kB];
      float4 wa0 = *(const float4*)(wAb + 0 * kH + k);
      float4 wa1 = *(const float4*)(wAb + 1 * kH + k);
      float4 wa2 = *(const float4*)(wAb + 2 * kH + k);
      float4 wa3 = *(const float4*)(wAb + 3 * kH + k);
      fma4(a0, h00, h01, h02, h03, wa0);
      fma4(a1, h00, h01, h02, h03, wa1);
      fma4(a2, h00, h01, h02, h03, wa2);
      fma4(a3, h00, h01, h02, h03, wa3);
      float4 wb0 = *(const float4*)(wBb + 0 * kH + k);
      float4 wb1 = *(const float4*)(wBb + 1 * kH + k);
      float4 wb2 = *(const float4*)(wBb + 2 * kH + k);
      float4 wb3 = *(const float4*)(wBb + 3 * kH + k);
      fma4(b0, h00, h01, h02, h03, wb0);
      fma4(b1, h00, h01, h02, h03, wb1);
      fma4(b2, h00, h01, h02, h03, wb2);
      fma4(b3, h00, h01, h02, h03, wb3);
      float4 wc0 = *(const float4*)(wCb + 0 * kH + k);
      float4 wc1 = *(const float4*)(wCb + 1 * kH + k);
      float4 wc2 = *(const float4*)(wCb + 2 * kH + k);
      float4 wc3 = *(const float4*)(wCb + 3 * kH + k);
      fma4(b0, h10, h11, h12, h13, wc0);
      fma4(b1, h10, h11, h12, h13, wc1);
      fma4(b2, h10, h11, h12, h13, wc2);
      fma4(b3, h10, h11, h12, h13, wc3);
    }
    // reduce K-halves in LDS
    if (kh == 1) {
      g2[cbase + 0][r] = a0; g2[cbase + 1][r] = a1;
      g2[cbase + 2][r] = a2; g2[cbase + 3][r] = a3;
      g2[8 + cbase + 0][r] = b0; g2[8 + cbase + 1][r] = b1;
      g2[8 + cbase + 2][r] = b2; g2[8 + cbase + 3][r] = b3;
    }
    __syncthreads();
    if (kh == 0) {
      g2[cbase + 0][r] += a0; g2[cbase + 1][r] += a1;
      g2[cbase + 2][r] += a2; g2[cbase + 3][r] += a3;
      g2[8 + cbase + 0][r] += b0; g2[8 + cbase + 1][r] += b1;
      g2[8 + cbase + 2][r] += b2; g2[8 + cbase + 3][r] += b3;
    }
    __syncthreads();
    {
      const int lay = tid >> 8;
      const int ul  = (tid >> 7) & 1;
      const int rr  = tid & (kB - 1);
      const bool act = (lay == 0) ? (p < kS) : (p >= 1);
      if (act) {
        const int base = 8 * lay + 4 * ul;
        float gi = sigm(g2[base + 0][rr]);
        float gf = sigm(g2[base + 1][rr]);
        float gg = tanhf(g2[base + 2][rr]);
        float go = sigm(g2[base + 3][rr]);
        float cc = fmaf(gf, c_sh[lay][ul][rr], gi * gg);
        c_sh[lay][ul][rr] = cc;
        float hv = go * tanhf(cc);
        float* hb = (lay == 0) ? (hT0 + (p & 1) * kHB) : (hT1 + ((p + 1) & 1) * kHB);
        hb[(2 * n + ul) * kB + rr] = hv;
      }
    }
    gbar(ws, n, ++gen);
  }

  // ---------------- restage LDS for decoder ----------------
  for (int i = tid; i < 8 * kH; i += NT) {
    int c = i >> 9, k = i & (kH - 1);
    int gc = ((c & 4) ? 2 * n + 1 : 2 * n) + (c & 3) * kH;
    wA[c][k] = dw_hh0[gc * kH + k];
    wB[c][k] = dw_ih1[gc * kH + k];
    wC[c][k] = dw_hh1[gc * kH + k];
  }
  for (int i = tid; i < kH; i += NT) fc_sh[i] = fc_w[n * kH + i];
  if (tid < 8) {
    int gc = ((tid & 4) ? 2 * n + 1 : 2 * n) + (tid & 3) * kH;
    bC_sh[tid] = db_ih1[gc] + db_hh1[gc];
  }
  const float fcb = fc_b[n];
  __syncthreads();

  // ---------------- decoder: 256 greedy steps, 3 barriers each ----------------
  // step t: h0 read buf t&1, write (t&1)^1 ; h1 read t&1, write (t&1)^1
#pragma unroll 1
  for (int t = 1; t <= kT - 1; ++t) {
    // ---- D1: cell0 ----
    int tok;
    if (t == 1) {
      tok = trg[r * kT];
    } else {
      unsigned long long pk = P[((t - 1) & 1) * kB + r];
      tok = 255 - (int)(unsigned)(pk & 0xffffffffull);
    }
    {
      float a0 = 0.f, a1 = 0.f, a2 = 0.f, a3 = 0.f;
      if (kh == 0) {
        const float* lp = dlut + ((size_t)n * kV + tok) * 8 + cbase;
        a0 = lp[0]; a1 = lp[1]; a2 = lp[2]; a3 = lp[3];
      }
      const float* h0p = hT0 + (t & 1) * kHB + kbase * kB + r;
      const float* wAb = &wA[cbase][0] + kbase;
#pragma unroll 2
      for (int k4 = 0; k4 < kH / 8; ++k4) {
        int k = k4 * 4;
        float h00 = h0p[(k + 0) * kB], h01 = h0p[(k + 1) * kB];
        float h02 = h0p[(k + 2) * kB], h03 = h0p[(k + 3) * kB];
        float4 wa0 = *(const float4*)(wAb + 0 * kH + k);
        float4 wa1 = *(const float4*)(wAb + 1 * kH + k);
        float4 wa2 = *(const float4*)(wAb + 2 * kH + k);
        float4 wa3 = *(const float4*)(wAb + 3 * kH + k);
        fma4(a0, h00, h01, h02, h03, wa0);
        fma4(a1, h00, h01, h02, h03, wa1);
        fma4(a2, h00, h01, h02, h03, wa2);
        fma4(a3, h00, h01, h02, h03, wa3);
      }
      if (kh == 1) {
        g2[cbase + 0][r] = a0; g2[cbase + 1][r] = a1;
        g2[cbase + 2][r] = a2; g2[cbase + 3][r] = a3;
      }
      __syncthreads();
      if (kh == 0) {
        g2[cbase + 0][r] += a0; g2[cbase + 1][r] += a1;
        g2[cbase + 2][r] += a2; g2[cbase + 3][r] += a3;
      }
      __syncthreads();
      if (tid < 256) {
        const int ul = tid >> 7, rr = tid & (kB - 1);
        const int base = 4 * ul;
        float gi = sigm(g2[base + 0][rr]);
        float gf = sigm(g2[base + 1][rr]);
        float gg = tanhf(g2[base + 2][rr]);
        float go = sigm(g2[base + 3][rr]);
        float cc = fmaf(gf, c_sh[0][ul][rr], gi * gg);
        c_sh[0][ul][rr] = cc;
        (hT0 + ((t & 1) ^ 1) * kHB)[(2 * n + ul) * kB + rr] = go * tanhf(cc);
      }
    }
    gbar(ws, n, ++gen);

    // ---- D2: cell1 (+ reset next argmax buffer) ----
    {
      float b0, b1, b2, b3;
      if (kh == 0) {
        b0 = bC_sh[cbase + 0]; b1 = bC_sh[cbase + 1];
        b2 = bC_sh[cbase + 2]; b3 = bC_sh[cbase + 3];
      } else {
        b0 = b1 = b2 = b3 = 0.f;
      }
      const float* h0n = hT0 + ((t & 1) ^ 1) * kHB + kbase * kB + r;
      const float* h1p = hT1 + (t & 1) * kHB + kbase * kB + r;
      const float* wBb = &wB[cbase][0] + kbase;
      const float* wCb = &wC[cbase][0] + kbase;
#pragma unroll 2
      for (int k4 = 0; k4 < kH / 8; ++k4) {
        int k = k4 * 4;
        float h00 = h0n[(k + 0) * kB], h01 = h0n[(k + 1) * kB];
        float h02 = h0n[(k + 2) * kB], h03 = h0n[(k + 3) * kB];
        float h10 = h1p[(k + 0) * kB], h11 = h1p[(k + 1) * kB];
        float h12 = h1p[(k + 2) * kB], h13 = h1p[(k + 3) * kB];
        float4 wb0 = *(const float4*)(wBb + 0 * kH + k);
        float4 wb1 = *(const float4*)(wBb + 1 * kH + k);
        float4 wb2 = *(const float4*)(wBb + 2 * kH + k);
        float4 wb3 = *(const float4*)(wBb + 3 * kH + k);
        fma4(b0, h00, h01, h02, h03, wb0);
        fma4(b1, h00, h01, h02, h03, wb1);
        fma4(b2, h00, h01, h02, h03, wb2);
        fma4(b3, h00, h01, h02, h03, wb3);
        float4 wc0 = *(const float4*)(wCb + 0 * kH + k);
        float4 wc1 = *(const float4*)(wCb + 1 * kH + k);
        float4 wc2 = *(const float4*)(wCb + 2 * kH + k);
        float4 wc3 = *(const float4*)(wCb + 3 * kH + k);
        fma4(b0, h10, h11, h12, h13, wc0);
        fma4(b1, h10, h11, h12, h13, wc1);
        fma4(b2, h10, h11, h12, h13, wc2);
        fma4(b3, h10, h11, h12, h13, wc3);
      }
      if (kh == 1) {
        g2[cbase + 0][r] = b0; g2[cbase + 1][r] = b1;
        g2[cbase + 2][r] = b2; g2[cbase + 3][r] = b3;
      }
      __syncthreads();
      if (kh == 0) {
        g2[cbase + 0][r] += b0; g2[cbase + 1][r] += b1;
        g2[cbase + 2][r] += b2; g2[cbase + 3][r] += b3;
      }
      if (tid < kB) P[(t & 1) * kB + tid] = 0ull;  // reset this step's argmax buf
      __syncthreads();
      if (tid < 256) {
        const int ul = tid >> 7, rr = tid & (kB - 1);
        const int base = 4 * ul;
        float gi = sigm(g2[base + 0][rr]);
        float gf = sigm(g2[base + 1][rr]);
        float gg = tanhf(g2[base + 2][rr]);
        float go = sigm(g2[base + 3][rr]);
        float cc = fmaf(gf, c_sh[1][ul][rr], gi * gg);
        c_sh[1][ul][rr] = cc;
        (hT1 + ((t & 1) ^ 1) * kHB)[(2 * n + ul) * kB + rr] = go * tanhf(cc);
      }
    }
    gbar(ws, n, ++gen);

    // ---- D3: fc (col n) + packed atomic argmax ----
    {
      const float* h1n = hT1 + ((t & 1) ^ 1) * kHB;
      const int kq = tid >> 7;  // K-quarter
      float part = 0.f;
      const float* hp = h1n + (kq * 128) * kB + r;
      const float* fp = fc_sh + kq * 128;
#pragma unroll 4
      for (int k4 = 0; k4 < 32; ++k4) {
        int k = k4 * 4;
        float4 w = *(const float4*)(fp + k);
        part = fmaf(hp[(k + 0) * kB], w.x, part);
        part = fmaf(hp[(k + 1) * kB], w.y, part);
        part = fmaf(hp[(k + 2) * kB], w.z, part);
        part = fmaf(hp[(k + 3) * kB], w.w, part);
      }
      ((float*)g2)[kq * kB + r] = part;
      __syncthreads();
      if (tid < kB) {
        float* gf = (float*)g2;
        float logit = gf[tid] + gf[kB + tid] + gf[2 * kB + tid] + gf[3 * kB + tid] + fcb;
        out[((size_t)tid * 256 + (t - 1)) * 256 + n] = logit;
        unsigned bits = __float_as_uint(logit);
        unsigned key = (bits & 0x80000000u) ? ~bits : (bits | 0x80000000u);
        unsigned long long pk =
            ((unsigned long long)key << 32) | (unsigned long long)(255 - n);
        atomicMax(&P[(t & 1) * kB + tid], pk);
      }
    }
    gbar(ws, n, ++gen);
  }
}

extern "C" void kernel_launch(void* const* d_in, const int* in_sizes, int n_in,
                              void* d_out, int out_size, void* d_ws, size_t ws_size,
                              hipStream_t stream) {
  (void)in_sizes; (void)n_in; (void)out_size; (void)ws_size;
  hipMemsetAsync(d_ws, 0, WS_ZERO, stream);  // barrier flags + argmax bufs + h buffers
  hipLaunchKernelGGL(seq2seq_persistent, dim3(NB), dim3(NT), 0, stream,
    (const int*)d_in[0], (const int*)d_in[1],
    (const float*)d_in[2],
    (const float*)d_in[3], (const float*)d_in[4],
    (const float*)d_in[5], (const float*)d_in[6],
    (const float*)d_in[7], (const float*)d_in[8],
    (const float*)d_in[9], (const float*)d_in[10],
    (const float*)d_in[11],
    (const float*)d_in[12], (const float*)d_in[13],
    (const float*)d_in[14], (const float*)d_in[15],
    (const float*)d_in[16], (const float*)d_in[17],
    (const float*)d_in[18], (const float*)d_in[19],
    (const float*)d_in[20], (const float*)d_in[21],
    (float*)d_out, (char*)d_ws);
}

// Round 4
// 44095.105 us; speedup vs baseline: 1.5454x; 1.3738x over previous
//
#include <hip/hip_runtime.h>

#define NB 256
#define NT 1024

namespace {
constexpr int kB = 128;
constexpr int kS = 1024;
constexpr int kT = 257;
constexpr int kV = 256;
constexpr int kE = 128;
constexpr int kH = 512;
constexpr int kHB = kH * kB;  // 65536 floats per h buffer
// ws layout
constexpr size_t WS_REL  = 0;                                   // u32 release word
constexpr size_t WS_ARR  = 1024;                                // 256 flags, 64B apart
constexpr size_t WS_P    = 18432;                               // packed argmax [2][kB]
constexpr size_t WS_HT   = 20480;                               // [4][kH][kB] h buffers
constexpr size_t WS_ELUT = WS_HT + sizeof(float) * (size_t)(4 * kHB);
constexpr size_t WS_DLUT = WS_ELUT + sizeof(float) * (size_t)(NB * kV * 8);
constexpr size_t WS_ZERO = WS_HT + sizeof(float) * (size_t)(4 * kHB);
}

__device__ __forceinline__ float sigm(float x) { return 1.0f / (1.0f + expf(-x)); }

// Contention-free grid barrier: per-block arrival flags (64B apart, release
// stores), block 0 aggregates, single release word broadcast.
__device__ __forceinline__ void gbar(char* ws, int n, unsigned gen) {
  __syncthreads();
  const int tid = threadIdx.x;
  unsigned* rel = (unsigned*)(ws + WS_REL);
  unsigned* arr = (unsigned*)(ws + WS_ARR);
  if (n == 0) {
    if (tid >= 1 && tid < NB) {
      while (__hip_atomic_load(&arr[tid * 16], __ATOMIC_RELAXED,
                               __HIP_MEMORY_SCOPE_AGENT) < gen)
        __builtin_amdgcn_s_sleep(1);
      __builtin_amdgcn_fence(__ATOMIC_ACQUIRE, "agent");
    }
    __syncthreads();
    if (tid == 0)
      __hip_atomic_store(rel, gen, __ATOMIC_RELEASE, __HIP_MEMORY_SCOPE_AGENT);
  } else {
    if (tid == 0) {
      __hip_atomic_store(&arr[n * 16], gen, __ATOMIC_RELEASE,
                         __HIP_MEMORY_SCOPE_AGENT);
      while (__hip_atomic_load(rel, __ATOMIC_RELAXED,
                               __HIP_MEMORY_SCOPE_AGENT) < gen)
        __builtin_amdgcn_s_sleep(1);
      __builtin_amdgcn_fence(__ATOMIC_ACQUIRE, "agent");
    }
  }
  __syncthreads();
}

__device__ __forceinline__ void fma4(float& acc, float h0, float h1, float h2,
                                     float h3, const float4& wv) {
  acc = fmaf(h0, wv.x, acc);
  acc = fmaf(h1, wv.y, acc);
  acc = fmaf(h2, wv.z, acc);
  acc = fmaf(h3, wv.w, acc);
}

__global__ __launch_bounds__(NT) void seq2seq_persistent(
    const int* __restrict__ src, const int* __restrict__ trg,
    const float* __restrict__ enc_emb,
    const float* __restrict__ ew_ih0, const float* __restrict__ ew_hh0,
    const float* __restrict__ eb_ih0, const float* __restrict__ eb_hh0,
    const float* __restrict__ ew_ih1, const float* __restrict__ ew_hh1,
    const float* __restrict__ eb_ih1, const float* __restrict__ eb_hh1,
    const float* __restrict__ dec_emb,
    const float* __restrict__ dw_ih0, const float* __restrict__ dw_hh0,
    const float* __restrict__ db_ih0, const float* __restrict__ db_hh0,
    const float* __restrict__ dw_ih1, const float* __restrict__ dw_hh1,
    const float* __restrict__ db_ih1, const float* __restrict__ db_hh1,
    const float* __restrict__ fc_w, const float* __restrict__ fc_b,
    float* __restrict__ out, char* __restrict__ ws)
{
  // Block n owns hidden units u0=2n, u1=2n+1: 8 gate columns per weight
  // matrix. Col c (0..7): gc = (c>=4 ? 2n+1 : 2n) + (c&3)*kH.
  // Thread (r, kg): batch row r = tid&127, K-group kg = tid>>7 (64 K each).
  // Each thread computes partials for ALL 8 cols over its K-group -> each h
  // element is read exactly once per block.
  __shared__ float wA[8][kH];        // enc: w_hh0 | dec: w_hh0
  __shared__ float wB[8][kH];        // enc: w_ih1 | dec: w_ih1
  __shared__ float wC[8][kH];        // enc: w_hh1 | dec: w_hh1
  __shared__ float fc_sh[kH];
  __shared__ float part[8][16][kB];  // [kg][L0 cols 0..7 | L1 cols 8..15][r]

  const int tid = threadIdx.x;
  const int n   = blockIdx.x;
  const int r   = tid & (kB - 1);
  const int kg  = tid >> 7;          // 0..7
  const int kbase = kg * 64;
  // epilogue role (tid < 512): layer = tid>>8, unit = (tid>>7)&1
  const int lay = tid >> 8;          // 0..3 (0,1 are epilogue layers)
  const int ul  = (tid >> 7) & 1;

  unsigned long long* P = (unsigned long long*)(ws + WS_P);
  float* hT0 = (float*)(ws + WS_HT);  // [2][kH][kB] transposed h, layer0
  float* hT1 = hT0 + 2 * kHB;         // layer1
  float* elut = (float*)(ws + WS_ELUT);
  float* dlut = (float*)(ws + WS_DLUT);

  float creg = 0.0f;                       // persistent cell state (epilogue thr)
  float bias1[4] = {0.f, 0.f, 0.f, 0.f};   // layer-1 gate biases (lay==1 thr)

  // ---------------- one-time init ----------------
  for (int i = tid; i < 8 * kH; i += NT) {
    int c = i >> 9, k = i & (kH - 1);
    int gc = ((c & 4) ? 2 * n + 1 : 2 * n) + (c & 3) * kH;
    wA[c][k] = ew_hh0[gc * kH + k];
    wB[c][k] = ew_ih1[gc * kH + k];
    wC[c][k] = ew_hh1[gc * kH + k];
  }
  if (lay == 1) {
#pragma unroll
    for (int g = 0; g < 4; ++g) {
      int gc = (ul ? 2 * n + 1 : 2 * n) + g * kH;
      bias1[g] = eb_ih1[gc] + eb_hh1[gc];
    }
  }
  // token LUTs: lut[v][c] = emb[v,:] @ w_ih0[gc,:] + b_ih0 + b_hh0
  for (int e = tid; e < kV * 8; e += NT) {
    int v = e >> 3, c = e & 7;
    int gc = ((c & 4) ? 2 * n + 1 : 2 * n) + (c & 3) * kH;
    float ae = eb_ih0[gc] + eb_hh0[gc];
    float ad = db_ih0[gc] + db_hh0[gc];
    for (int ee = 0; ee < kE; ++ee) {
      ae = fmaf(enc_emb[v * kE + ee], ew_ih0[gc * kE + ee], ae);
      ad = fmaf(dec_emb[v * kE + ee], dw_ih0[gc * kE + ee], ad);
    }
    elut[((size_t)n * kV + v) * 8 + c] = ae;
    dlut[((size_t)n * kV + v) * 8 + c] = ad;
  }
  __syncthreads();

  unsigned gen = 0;

  // ---------------- encoder: layers 0/1 pipelined, 1 barrier per step --------
  // phase p: L0 computes t=p (p<kS), L1 computes t'=p-1 (p>=1).
  // hT0: read (p+1)&1, write p&1 ; hT1: read p&1, write (p+1)&1
#pragma unroll 1
  for (int p = 0; p <= kS; ++p) {
    float a0[8], a1[8];
    if (kg == 0) {
      int tok = (p < kS) ? src[r * kS + p] : 0;
      const float* lp = elut + ((size_t)n * kV + tok) * 8;
#pragma unroll
      for (int c = 0; c < 8; ++c) a0[c] = lp[c];
    } else {
#pragma unroll
      for (int c = 0; c < 8; ++c) a0[c] = 0.f;
    }
#pragma unroll
    for (int c = 0; c < 8; ++c) a1[c] = 0.f;

    const float* h0p = hT0 + ((p + 1) & 1) * kHB + kbase * kB + r;
    const float* h1p = hT1 + (p & 1) * kHB + kbase * kB + r;
#pragma unroll 2
    for (int k4 = 0; k4 < 16; ++k4) {
      int k = k4 * 4;
      float h00 = h0p[(k + 0) * kB], h01 = h0p[(k + 1) * kB];
      float h02 = h0p[(k + 2) * kB], h03 = h0p[(k + 3) * kB];
      float h10 = h1p[(k + 0) * kB], h11 = h1p[(k + 1) * kB];
      float h12 = h1p[(k + 2) * kB], h13 = h1p[(k + 3) * kB];
#pragma unroll
      for (int c = 0; c < 8; ++c) {
        float4 wa = *(const float4*)(&wA[c][kbase + k]);
        fma4(a0[c], h00, h01, h02, h03, wa);
      }
#pragma unroll
      for (int c = 0; c < 8; ++c) {
        float4 wb = *(const float4*)(&wB[c][kbase + k]);
        fma4(a1[c], h00, h01, h02, h03, wb);
        float4 wc = *(const float4*)(&wC[c][kbase + k]);
        fma4(a1[c], h10, h11, h12, h13, wc);
      }
    }
#pragma unroll
    for (int c = 0; c < 8; ++c) {
      part[kg][c][r] = a0[c];
      part[kg][8 + c][r] = a1[c];
    }
    __syncthreads();
    if (lay < 2) {
      const bool act = (lay == 0) ? (p < kS) : (p >= 1);
      if (act) {
        float s0 = 0.f, s1 = 0.f, s2 = 0.f, s3 = 0.f;
        const int cb = lay * 8 + ul * 4;
#pragma unroll
        for (int q = 0; q < 8; ++q) {
          s0 += part[q][cb + 0][r];
          s1 += part[q][cb + 1][r];
          s2 += part[q][cb + 2][r];
          s3 += part[q][cb + 3][r];
        }
        if (lay == 1) {
          s0 += bias1[0]; s1 += bias1[1]; s2 += bias1[2]; s3 += bias1[3];
        }
        float gi = sigm(s0), gf = sigm(s1), gg = tanhf(s2), go = sigm(s3);
        creg = fmaf(gf, creg, gi * gg);
        float hv = go * tanhf(creg);
        float* hb = (lay == 0) ? (hT0 + (p & 1) * kHB) : (hT1 + ((p + 1) & 1) * kHB);
        hb[(2 * n + ul) * kB + r] = hv;
      }
    }
    gbar(ws, n, ++gen);
  }

  // ---------------- restage LDS for decoder ----------------
  for (int i = tid; i < 8 * kH; i += NT) {
    int c = i >> 9, k = i & (kH - 1);
    int gc = ((c & 4) ? 2 * n + 1 : 2 * n) + (c & 3) * kH;
    wA[c][k] = dw_hh0[gc * kH + k];
    wB[c][k] = dw_ih1[gc * kH + k];
    wC[c][k] = dw_hh1[gc * kH + k];
  }
  for (int i = tid; i < kH; i += NT) fc_sh[i] = fc_w[n * kH + i];
  if (lay == 1) {
#pragma unroll
    for (int g = 0; g < 4; ++g) {
      int gc = (ul ? 2 * n + 1 : 2 * n) + g * kH;
      bias1[g] = db_ih1[gc] + db_hh1[gc];
    }
  }
  const float fcb = fc_b[n];
  __syncthreads();

  // ---------------- decoder: 256 greedy steps, 3 barriers each ----------------
  // step t: h0 read buf t&1, write (t&1)^1 ; h1 read t&1, write (t&1)^1
#pragma unroll 1
  for (int t = 1; t <= kT - 1; ++t) {
    // ---- D1: cell0 ----
    {
      float a0[8];
      if (kg == 0) {
        int tok;
        if (t == 1) {
          tok = trg[r * kT];
        } else {
          unsigned long long pk = P[((t - 1) & 1) * kB + r];
          tok = 255 - (int)(unsigned)(pk & 0xffffffffull);
        }
        const float* lp = dlut + ((size_t)n * kV + tok) * 8;
#pragma unroll
        for (int c = 0; c < 8; ++c) a0[c] = lp[c];
      } else {
#pragma unroll
        for (int c = 0; c < 8; ++c) a0[c] = 0.f;
      }
      const float* h0p = hT0 + (t & 1) * kHB + kbase * kB + r;
#pragma unroll 2
      for (int k4 = 0; k4 < 16; ++k4) {
        int k = k4 * 4;
        float h00 = h0p[(k + 0) * kB], h01 = h0p[(k + 1) * kB];
        float h02 = h0p[(k + 2) * kB], h03 = h0p[(k + 3) * kB];
#pragma unroll
        for (int c = 0; c < 8; ++c) {
          float4 wa = *(const float4*)(&wA[c][kbase + k]);
          fma4(a0[c], h00, h01, h02, h03, wa);
        }
      }
#pragma unroll
      for (int c = 0; c < 8; ++c) part[kg][c][r] = a0[c];
      __syncthreads();
      if (lay == 0) {
        float s0 = 0.f, s1 = 0.f, s2 = 0.f, s3 = 0.f;
        const int cb = ul * 4;
#pragma unroll
        for (int q = 0; q < 8; ++q) {
          s0 += part[q][cb + 0][r];
          s1 += part[q][cb + 1][r];
          s2 += part[q][cb + 2][r];
          s3 += part[q][cb + 3][r];
        }
        float gi = sigm(s0), gf = sigm(s1), gg = tanhf(s2), go = sigm(s3);
        creg = fmaf(gf, creg, gi * gg);
        (hT0 + ((t & 1) ^ 1) * kHB)[(2 * n + ul) * kB + r] = go * tanhf(creg);
      }
    }
    gbar(ws, n, ++gen);

    // ---- D2: cell1 (+ reset this step's argmax buffer) ----
    {
      float a1[8];
#pragma unroll
      for (int c = 0; c < 8; ++c) a1[c] = 0.f;
      const float* h0n = hT0 + ((t & 1) ^ 1) * kHB + kbase * kB + r;
      const float* h1p = hT1 + (t & 1) * kHB + kbase * kB + r;
#pragma unroll 2
      for (int k4 = 0; k4 < 16; ++k4) {
        int k = k4 * 4;
        float h00 = h0n[(k + 0) * kB], h01 = h0n[(k + 1) * kB];
        float h02 = h0n[(k + 2) * kB], h03 = h0n[(k + 3) * kB];
        float h10 = h1p[(k + 0) * kB], h11 = h1p[(k + 1) * kB];
        float h12 = h1p[(k + 2) * kB], h13 = h1p[(k + 3) * kB];
#pragma unroll
        for (int c = 0; c < 8; ++c) {
          float4 wb = *(const float4*)(&wB[c][kbase + k]);
          fma4(a1[c], h00, h01, h02, h03, wb);
          float4 wc = *(const float4*)(&wC[c][kbase + k]);
          fma4(a1[c], h10, h11, h12, h13, wc);
        }
      }
#pragma unroll
      for (int c = 0; c < 8; ++c) part[kg][8 + c][r] = a1[c];
      if (tid < kB) P[(t & 1) * kB + tid] = 0ull;
      __syncthreads();
      if (lay == 1) {
        float s0 = 0.f, s1 = 0.f, s2 = 0.f, s3 = 0.f;
        const int cb = 8 + ul * 4;
#pragma unroll
        for (int q = 0; q < 8; ++q) {
          s0 += part[q][cb + 0][r];
          s1 += part[q][cb + 1][r];
          s2 += part[q][cb + 2][r];
          s3 += part[q][cb + 3][r];
        }
        s0 += bias1[0]; s1 += bias1[1]; s2 += bias1[2]; s3 += bias1[3];
        float gi = sigm(s0), gf = sigm(s1), gg = tanhf(s2), go = sigm(s3);
        creg = fmaf(gf, creg, gi * gg);
        (hT1 + ((t & 1) ^ 1) * kHB)[(2 * n + ul) * kB + r] = go * tanhf(creg);
      }
    }
    gbar(ws, n, ++gen);

    // ---- D3: fc (col n) + packed atomic argmax ----
    {
      const float* h1n = hT1 + ((t & 1) ^ 1) * kHB + kbase * kB + r;
      const float* fp = fc_sh + kbase;
      float ps = 0.f;
#pragma unroll 4
      for (int k4 = 0; k4 < 16; ++k4) {
        int k = k4 * 4;
        float4 w = *(const float4*)(fp + k);
        ps = fmaf(h1n[(k + 0) * kB], w.x, ps);
        ps = fmaf(h1n[(k + 1) * kB], w.y, ps);
        ps = fmaf(h1n[(k + 2) * kB], w.z, ps);
        ps = fmaf(h1n[(k + 3) * kB], w.w, ps);
      }
      ((float*)part)[kg * kB + r] = ps;
      __syncthreads();
      if (tid < kB) {
        const float* pf = (const float*)part;
        float logit = fcb;
#pragma unroll
        for (int q = 0; q < 8; ++q) logit += pf[q * kB + tid];
        out[((size_t)tid * 256 + (t - 1)) * 256 + n] = logit;
        unsigned bits = __float_as_uint(logit);
        unsigned key = (bits & 0x80000000u) ? ~bits : (bits | 0x80000000u);
        unsigned long long pk =
            ((unsigned long long)key << 32) | (unsigned long long)(255 - n);
        atomicMax(&P[(t & 1) * kB + tid], pk);
      }
    }
    gbar(ws, n, ++gen);
  }
}

extern "C" void kernel_launch(void* const* d_in, const int* in_sizes, int n_in,
                              void* d_out, int out_size, void* d_ws, size_t ws_size,
                              hipStream_t stream) {
  (void)in_sizes; (void)n_in; (void)out_size; (void)ws_size;
  hipMemsetAsync(d_ws, 0, WS_ZERO, stream);  // barrier flags + argmax bufs + h buffers
  hipLaunchKernelGGL(seq2seq_persistent, dim3(NB), dim3(NT), 0, stream,
    (const int*)d_in[0], (const int*)d_in[1],
    (const float*)d_in[2],
    (const float*)d_in[3], (const float*)d_in[4],
    (const float*)d_in[5], (const float*)d_in[6],
    (const float*)d_in[7], (const float*)d_in[8],
    (const float*)d_in[9], (const float*)d_in[10],
    (const float*)d_in[11],
    (const float*)d_in[12], (const float*)d_in[13],
    (const float*)d_in[14], (const float*)d_in[15],
    (const float*)d_in[16], (const float*)d_in[17],
    (const float*)d_in[18], (const float*)d_in[19],
    (const float*)d_in[20], (const float*)d_in[21],
    (float*)d_out, (char*)d_ws);
}